// Round 11
// baseline (131.373 us; speedup 1.0000x reference)
//
#include <hip/hip_runtime.h>

#define L_TOTAL   32768
#define E_DIM     64
#define K_TOTAL   1024
#define NT_TOTAL  64                  // K_TOTAL / 16
#define OUT_STRIDE 2097152            // L_TOTAL * E_DIM

// compact staging record per nt = 1088 words (4352 B):
//   [0,256)    kt0 hi frags (64 lanes x 16 B)
//   [256,512)  kt1 hi
//   [512,768)  kt0 lo
//   [768,1024) kt1 lo
//   [1024,1088) norms (64 f32, dup x4 over quads)
#define NT_WORDS   1088
#define QT_WORDS   (16 * NT_WORDS)    // one quarter = 17408 words = 69632 B

// ws layout (bytes)
#define WS_EBUF 0u                    // 64 * 4352 = 278528 B
#define WS_PART 278528u               // float2 [4 quarter][32768 lat] = 1 MB

typedef _Float16 half_t;
typedef _Float16 half8  __attribute__((ext_vector_type(8)));
typedef float    floatx4 __attribute__((ext_vector_type(4)));

// ---------------------------------------------------------------------------
// Codebook fp32 -> compact staged records (f16 hi/lo fragments + norms).
// Fragment (nt,kt,lane) = e[nt*16 + (lane&15)][kt*32 + (lane>>4)*8 .. +8].
// Norm tree identical to R8 (verified absmax 19).
// ---------------------------------------------------------------------------
__global__ __launch_bounds__(128)
void vq_eswz_kernel(const float* __restrict__ emb, float* __restrict__ ebuf) {
    __shared__ float s_p[128];
    __shared__ float s_n[16];
    const int nt   = blockIdx.x;
    const int t    = threadIdx.x;
    const int kt   = t >> 6;
    const int lane = t & 63;
    const int q    = lane >> 4;
    const int ln   = lane & 15;

    const float* src = emb + (size_t)(nt * 16 + ln) * E_DIM + kt * 32 + q * 8;
    float4 v0 = *(const float4*)src;
    float4 v1 = *(const float4*)(src + 4);
    float f[8] = {v0.x, v0.y, v0.z, v0.w, v1.x, v1.y, v1.z, v1.w};

    half8 h, l;
    float s = 0.f;
    #pragma unroll
    for (int j = 0; j < 8; ++j) {
        half_t hh = (half_t)f[j];
        half_t ll = (half_t)(f[j] - (float)hh);
        h[j] = hh;
        l[j] = ll;
        s = fmaf(f[j], f[j], s);
    }
    float* rec = ebuf + (size_t)nt * NT_WORDS;
    *(half8*)(rec + kt * 256 + lane * 4)       = h;   // hi
    *(half8*)(rec + 512 + kt * 256 + lane * 4) = l;   // lo

    s_p[t] = s;
    __syncthreads();
    if (t < 16) {
        float n = 0.f;
        #pragma unroll
        for (int u = 0; u < 8; ++u)
            n += s_p[(u >> 2) * 64 + (u & 3) * 16 + t];
        s_n[t] = n;
    }
    __syncthreads();
    if (t < 64) rec[1024 + t] = s_n[t & 15];
}

// ---------------------------------------------------------------------------
// LDS-fed distance + argmin. Grid 2048 = 512 latent-groups(64) x 4 quarters.
// Block: stage quarter's 69.6 KB B into dynamic LDS (one barrier), then
// wave w scans nt-slice [w*4, w*4+4) over all 64 latents (rt=4, 24 MFMA per
// step) with ZERO in-loop global loads and ZERO in-loop barriers. B read via
// ds_read_b128, 1-deep register prefetch. A-frags converted in-register
// (exact R8 trees). Lexicographic argmin == numpy first occurrence.
// Per-quarter partials -> ws.  2 blocks/CU (LDS-bound), ~200 VGPR no-spill.
// ---------------------------------------------------------------------------
__global__ __launch_bounds__(256, 2)
void vq_dist_kernel(const float* __restrict__ x,
                    const float* __restrict__ ebuf,
                    float2* __restrict__ partial) {
    extern __shared__ float s_b[];       // QT_WORDS = 69632 B
    __shared__ float s_best[4][64];
    __shared__ int   s_bidx[4][64];

    const int tid     = threadIdx.x;
    const int wave    = tid >> 6;
    const int lane    = tid & 63;
    const int q       = lane >> 4;
    const int ln      = lane & 15;
    const int quarter = blockIdx.x & 3;
    const int mbase   = (blockIdx.x >> 2) * 64;

    // ---- stage the quarter's compact B: 4352 float4, 17 per thread, coalesced
    {
        const float4* src = (const float4*)(ebuf + (size_t)quarter * QT_WORDS);
        #pragma unroll
        for (int i = 0; i < 17; ++i)
            ((float4*)s_b)[i * 256 + tid] = src[i * 256 + tid];
    }

    // ---- A fragments (hi/lo) + row norms, 64 latents (rt=4), exact R8 trees
    half8 A[4][2][2];                  // [rt][kt][hi/lo]
    floatx4 xq[4];
    #pragma unroll
    for (int rt = 0; rt < 4; ++rt) {
        const float* xr = x + (size_t)(mbase + rt * 16 + ln) * E_DIM + q * 8;
        float sn = 0.f;
        #pragma unroll
        for (int kt = 0; kt < 2; ++kt) {
            float4 v0 = *(const float4*)(xr + kt * 32);
            float4 v1 = *(const float4*)(xr + kt * 32 + 4);
            float f[8] = {v0.x, v0.y, v0.z, v0.w, v1.x, v1.y, v1.z, v1.w};
            #pragma unroll
            for (int j = 0; j < 8; ++j) {
                half_t hh = (half_t)f[j];
                half_t ll = (half_t)(f[j] - (float)hh);
                A[rt][kt][0][j] = hh;
                A[rt][kt][1][j] = ll;
                sn = fmaf(f[j], f[j], sn);
            }
        }
        sn += __shfl_xor(sn, 16, 64);
        sn += __shfl_xor(sn, 32, 64);
        #pragma unroll
        for (int r = 0; r < 4; ++r)
            xq[rt][r] = __shfl(sn, q * 4 + r, 64);
    }

    float best[4][4];
    int   bidx[4][4];
    #pragma unroll
    for (int rt = 0; rt < 4; ++rt)
        #pragma unroll
        for (int r = 0; r < 4; ++r) { best[rt][r] = 3.402823466e+38f; bidx[rt][r] = 0x7fffffff; }

    __syncthreads();                     // staged B visible; the ONLY hot barrier

    // ---- 4-step scan of this wave's nt-slice, LDS-fed, 1-deep prefetch
    const int nl0 = wave * 4;            // local nt base within quarter
    half8 cb0, cb1, cb2, cb3, nb0, nb1, nb2, nb3;
    float cen, nen;
    {
        const float* rec = &s_b[nl0 * NT_WORDS];
        nb0 = *(const half8*)(rec + lane * 4);
        nb1 = *(const half8*)(rec + 256 + lane * 4);
        nb2 = *(const half8*)(rec + 512 + lane * 4);
        nb3 = *(const half8*)(rec + 768 + lane * 4);
        nen = rec[1024 + lane];
    }
    #pragma unroll 1
    for (int j = 0; j < 4; ++j) {
        cb0 = nb0; cb1 = nb1; cb2 = nb2; cb3 = nb3; cen = nen;
        if (j < 3) {
            const float* rec = &s_b[(nl0 + j + 1) * NT_WORDS];
            nb0 = *(const half8*)(rec + lane * 4);
            nb1 = *(const half8*)(rec + 256 + lane * 4);
            nb2 = *(const half8*)(rec + 512 + lane * 4);
            nb3 = *(const half8*)(rec + 768 + lane * 4);
            nen = rec[1024 + lane];
        }
        const int kg = (quarter * 16 + nl0 + j) * 16 + ln;
        #pragma unroll
        for (int rt = 0; rt < 4; ++rt) {
            floatx4 Ca = {0.f, 0.f, 0.f, 0.f};
            floatx4 Cb = {0.f, 0.f, 0.f, 0.f};
            Ca = __builtin_amdgcn_mfma_f32_16x16x32_f16(A[rt][0][0], cb0, Ca, 0, 0, 0);
            Ca = __builtin_amdgcn_mfma_f32_16x16x32_f16(A[rt][1][0], cb1, Ca, 0, 0, 0);
            Cb = __builtin_amdgcn_mfma_f32_16x16x32_f16(A[rt][0][1], cb0, Cb, 0, 0, 0);
            Cb = __builtin_amdgcn_mfma_f32_16x16x32_f16(A[rt][1][1], cb1, Cb, 0, 0, 0);
            Cb = __builtin_amdgcn_mfma_f32_16x16x32_f16(A[rt][0][0], cb2, Cb, 0, 0, 0);
            Cb = __builtin_amdgcn_mfma_f32_16x16x32_f16(A[rt][1][0], cb3, Cb, 0, 0, 0);
            #pragma unroll
            for (int r = 0; r < 4; ++r) {
                float dot = Ca[r] + Cb[r];
                // reference op order: (xx - 2*dot) + en, no FMA contraction
                float d = __fadd_rn(__fsub_rn(xq[rt][r], __fmul_rn(2.0f, dot)), cen);
                if (d < best[rt][r] || (d == best[rt][r] && kg < bidx[rt][r])) {
                    best[rt][r] = d; bidx[rt][r] = kg;
                }
            }
        }
    }

    // ---- argmin across the 16 col-lanes of each quad (ties -> lower index)
    #pragma unroll
    for (int o = 1; o < 16; o <<= 1) {
        #pragma unroll
        for (int rt = 0; rt < 4; ++rt)
            #pragma unroll
            for (int r = 0; r < 4; ++r) {
                float ob = __shfl_xor(best[rt][r], o, 64);
                int   oi = __shfl_xor(bidx[rt][r], o, 64);
                if (ob < best[rt][r] || (ob == best[rt][r] && oi < bidx[rt][r])) {
                    best[rt][r] = ob; bidx[rt][r] = oi;
                }
            }
    }
    if (ln == 0) {
        #pragma unroll
        for (int rt = 0; rt < 4; ++rt)
            #pragma unroll
            for (int r = 0; r < 4; ++r) {
                s_best[wave][rt * 16 + q * 4 + r] = best[rt][r];
                s_bidx[wave][rt * 16 + q * 4 + r] = bidx[rt][r];
            }
    }
    __syncthreads();

    // ---- merge the 4 wave-slices (ascending code ranges, lexicographic)
    if (tid < 64) {
        float b = 3.402823466e+38f;
        int   i = 0x7fffffff;
        #pragma unroll
        for (int w = 0; w < 4; ++w) {
            float pb = s_best[w][tid];
            int   pi = s_bidx[w][tid];
            if (pb < b || (pb == b && pi < i)) { b = pb; i = pi; }
        }
        partial[(size_t)quarter * L_TOTAL + mbase + tid] =
            make_float2(b, __int_as_float(i));
    }
}

// ---------------------------------------------------------------------------
// Merge 4 quarter-partials per latent (lexicographic == first occurrence),
// then coalesced epilogue: out0 = x, out1 = emb[idx], out2 = (x+q)-x.
// Grid 512 x 256 (64 latents / block).
// ---------------------------------------------------------------------------
__global__ __launch_bounds__(256)
void vq_epilogue_kernel(const float* __restrict__ x,
                        const float* __restrict__ emb,
                        const float2* __restrict__ partial,
                        float* __restrict__ out) {
    __shared__ int s_fin[64];
    const int tid  = threadIdx.x;
    const int base = blockIdx.x * 64;

    if (tid < 64) {
        float b = 3.402823466e+38f;
        int   i = 0x7fffffff;
        #pragma unroll
        for (int s = 0; s < 4; ++s) {
            float2 p = partial[(size_t)s * L_TOTAL + base + tid];
            int    pi = __float_as_int(p.y);
            if (p.x < b || (p.x == b && pi < i)) { b = p.x; i = pi; }
        }
        s_fin[tid] = i;
        out[3 * (size_t)OUT_STRIDE + base + tid] = (float)i;   // coalesced
    }
    __syncthreads();

    const size_t fb = (size_t)base * (E_DIM / 4);
    const float4* xg = (const float4*)x + fb;
    float4* o0 = (float4*)out + fb;
    float4* o1 = (float4*)(out + OUT_STRIDE) + fb;
    float4* o2 = (float4*)(out + 2 * (size_t)OUT_STRIDE) + fb;
    #pragma unroll
    for (int i = 0; i < 4; ++i) {
        const int f   = i * 256 + tid;
        const int row = f >> 4;
        const int col = (f & 15) * 4;
        const float4 xv = xg[f];
        const int idx = s_fin[row];
        const float4 qv = *(const float4*)(emb + (size_t)idx * E_DIM + col);
        float4 z;
        z.x = __fsub_rn(__fadd_rn(xv.x, qv.x), xv.x);
        z.y = __fsub_rn(__fadd_rn(xv.y, qv.y), xv.y);
        z.z = __fsub_rn(__fadd_rn(xv.z, qv.z), xv.z);
        z.w = __fsub_rn(__fadd_rn(xv.w, qv.w), xv.w);
        o0[f] = xv;
        o1[f] = qv;
        o2[f] = z;
    }
}

// ---------------------------------------------------------------------------
extern "C" void kernel_launch(void* const* d_in, const int* in_sizes, int n_in,
                              void* d_out, int out_size, void* d_ws, size_t ws_size,
                              hipStream_t stream) {
    const float* x   = (const float*)d_in[0];
    const float* emb = (const float*)d_in[1];
    float* out = (float*)d_out;

    float*  ebuf = (float*)((char*)d_ws + WS_EBUF);
    float2* part = (float2*)((char*)d_ws + WS_PART);

    hipLaunchKernelGGL(vq_eswz_kernel, dim3(NT_TOTAL), dim3(128), 0, stream,
                       emb, ebuf);
    hipLaunchKernelGGL(vq_dist_kernel, dim3(2048), dim3(256),
                       QT_WORDS * sizeof(float), stream,
                       x, ebuf, part);
    hipLaunchKernelGGL(vq_epilogue_kernel, dim3(512), dim3(256), 0, stream,
                       x, emb, part, out);
}